// Round 13
// baseline (368.596 us; speedup 1.0000x reference)
//
#include <hip/hip_runtime.h>

// GCN: h' = relu(A @ (h @ W) + b) x3, last layer no relu.
// Round 13: XCD-aware COLUMN-PARTITIONED aggregation. Agg splits the feature
// dim into 4 groups x 32 cols (sup slice 3.2MB < 4MB XCD L2), group tied to
// XCD via blockIdx&3 (blocks round-robin XCDs by blockIdx%8) -> each XCD's
// L2 holds only its slice; gathers become single 64B lines. GEMMs unfused
// (separate MFMA kernels). Edge lists sentinel-padded (mult of 16), 4B
// packed records (src16 | bf16(w)<<16).

constexpr int NN = 50000;          // nodes
constexpr int NE = 800000;         // edges
constexpr int NB = (NN + 127) >> 7;          // 391 buckets (dst >> 7)
constexpr int CAP = 4608;                    // padded bucket capacity
constexpr int PART_CHUNK = 4096;             // edges per partition block
constexpr int PART_GRID = (NE + PART_CHUNK - 1) / PART_CHUNK;  // 196

typedef __attribute__((ext_vector_type(8))) short bf16x8;
typedef __attribute__((ext_vector_type(4))) float floatx4;

__device__ inline unsigned short f2bf(float f) {          // RNE fp32->bf16
    unsigned u = __float_as_uint(f);
    u += 0x7fffu + ((u >> 16) & 1u);
    return (unsigned short)(u >> 16);
}
__device__ inline float bflo(unsigned v) { return __uint_as_float(v << 16); }
__device__ inline float bfhi(unsigned v) { return __uint_as_float(v & 0xffff0000u); }

// ---------------- binned edge sort (padded buckets) ----------------

__global__ __launch_bounds__(256) void k_part(
        const int* __restrict__ src, const int* __restrict__ dst,
        const float* __restrict__ w, int* __restrict__ bfill,
        int2* __restrict__ ep) {
    __shared__ int hist[NB], base[NB], off[NB];
    int tid = threadIdx.x;
    for (int b = tid; b < NB; b += 256) { hist[b] = 0; off[b] = 0; }
    __syncthreads();

    int e0 = blockIdx.x * PART_CHUNK;
    int  sreg[16]; int wreg[16]; short breg[16];
#pragma unroll
    for (int i = 0; i < 16; ++i) {
        int e = e0 + i * 256 + tid;
        if (e < NE) {
            int d = dst[e];
            int b = d >> 7;
            sreg[i] = (src[e] & 0xffff) | ((d & 127) << 16);
            wreg[i] = __float_as_int(w[e]);
            breg[i] = (short)b;
            atomicAdd(&hist[b], 1);
        } else breg[i] = -1;
    }
    __syncthreads();
    for (int b = tid; b < NB; b += 256)
        base[b] = b * CAP + atomicAdd(&bfill[b], hist[b]);
    __syncthreads();
#pragma unroll
    for (int i = 0; i < 16; ++i) {
        if (breg[i] >= 0) {
            int b = breg[i];
            int p = atomicAdd(&off[b], 1);
            ep[base[b] + p] = make_int2(sreg[i], wreg[i]);
        }
    }
}

// Within-bucket dst sort with per-node padding to multiple of 16.
// Emits packed 4B records: src16 | bf16(w)<<16; pad slots are 0 (w=0).
__global__ __launch_bounds__(256) void k_sort(
        const int2* __restrict__ ep, const int* __restrict__ bfill,
        unsigned* __restrict__ es, int2* __restrict__ begend) {
    __shared__ int cnt[128], base[128], fl[128];
    __shared__ int s_total;
    int b  = blockIdx.x;
    int n0 = b << 7;
    int nn = min(128, NN - n0);
    int t  = threadIdx.x;
    if (t < 128) { cnt[t] = 0; fl[t] = 0; }
    __syncthreads();
    int bbase = b * CAP;
    int beg = bbase, end = bbase + bfill[b];
    for (int e = beg + t; e < end; e += 256)
        atomicAdd(&cnt[(ep[e].x >> 16) & 127], 1);
    __syncthreads();
    int cp = (t < 128) ? ((cnt[t] + 15) & ~15) : 0;
    if (t < 128) base[t] = cp;
    __syncthreads();
    for (int off = 1; off < 128; off <<= 1) {
        int add = (t >= off && t < 128) ? base[t - off] : 0;
        __syncthreads();
        if (t < 128) base[t] += add;     // inclusive scan of padded counts
        __syncthreads();
    }
    if (t == 127) s_total = base[127];
    __syncthreads();
    int total = s_total;
    for (int i = t; i < total + 16; i += 256) es[bbase + i] = 0u;
    if (t < nn) {
        int off = base[t] - cp;
        begend[n0 + t] = make_int2(bbase + off, bbase + off + cp);
    }
    __syncthreads();
    for (int e = beg + t; e < end; e += 256) {
        int2 v = ep[e];
        int d = (v.x >> 16) & 127;
        int off = base[d] - ((cnt[d] + 15) & ~15);
        int pos = bbase + off + atomicAdd(&fl[d], 1);
        es[pos] = (unsigned)(v.x & 0xffff) |
                  ((unsigned)f2bf(__int_as_float(v.y)) << 16);
    }
}

// ---------------- weight transpose+convert + bfill zero --------------------

__global__ void k_prep(
        const float* __restrict__ W0, const float* __restrict__ W1,
        const float* __restrict__ W2, const float* __restrict__ W3,
        unsigned short* __restrict__ T0, unsigned short* __restrict__ T1,
        unsigned short* __restrict__ T2, unsigned short* __restrict__ T3,
        int* __restrict__ bfill) {
    int b = blockIdx.x;              // 0..448
    if (b == 448) {
        for (int i = threadIdx.x; i < NB; i += 128) bfill[i] = 0;
        return;
    }
    const float* W; unsigned short* T; int N, n;
    if (b < 128)      { W = W0; T = T0; N = 128; n = b; }
    else if (b < 256) { W = W1; T = T1; N = 128; n = b - 128; }
    else if (b < 384) { W = W2; T = T2; N = 128; n = b - 256; }
    else              { W = W3; T = T3; N = 64;  n = b - 384; }
    int k = threadIdx.x;             // 0..127
    T[n * 128 + k] = f2bf(W[(size_t)k * N + n]);
}

// ---------------- GEMM 0 (MFMA): sup = bf16(x @ W0), x fp32 ----------------

__device__ inline bf16x8 ldA_f32(const float* A, size_t off) {
    float4 u = *(const float4*)&A[off];
    float4 v = *(const float4*)&A[off + 4];
    bf16x8 r;
    r[0] = (short)f2bf(u.x); r[1] = (short)f2bf(u.y);
    r[2] = (short)f2bf(u.z); r[3] = (short)f2bf(u.w);
    r[4] = (short)f2bf(v.x); r[5] = (short)f2bf(v.y);
    r[6] = (short)f2bf(v.z); r[7] = (short)f2bf(v.w);
    return r;
}

__global__ __launch_bounds__(256) void k_gemm0(
        const float* __restrict__ A,            // [M][128] fp32
        const unsigned short* __restrict__ Wt,  // [128][128] bf16
        unsigned short* __restrict__ C,         // [M][128] bf16
        int M) {
    constexpr int STR = 136;
    __shared__ unsigned short sWt[128 * STR];

    const int tid = threadIdx.x;
#pragma unroll
    for (int i = 0; i < 8; ++i) {
        int c = i * 256 + tid;
        int row = c >> 4, col = (c & 15) * 8;
        *(uint4*)&sWt[row * STR + col] = *(const uint4*)&Wt[row * 128 + col];
    }

    const int wv = tid >> 6;
    const int ln = tid & 63;
    const int m  = ln & 15;
    const int qd = ln >> 4;

    int gr  = blockIdx.x * 64 + wv * 16 + m;
    int grc = (gr < M) ? gr : (M - 1);
    bf16x8 af[4];
#pragma unroll
    for (int s = 0; s < 4; ++s)
        af[s] = ldA_f32(A, (size_t)grc * 128 + s * 32 + qd * 8);

    __syncthreads();

    floatx4 acc[8];
#pragma unroll
    for (int c = 0; c < 8; ++c) {
        acc[c] = (floatx4){0.f, 0.f, 0.f, 0.f};
#pragma unroll
        for (int s = 0; s < 4; ++s) {
            bf16x8 bf = *(const bf16x8*)&sWt[(c * 16 + m) * STR + s * 32 + qd * 8];
            acc[c] = __builtin_amdgcn_mfma_f32_16x16x32_bf16(af[s], bf, acc[c], 0, 0, 0);
        }
    }

    int row0 = blockIdx.x * 64 + wv * 16 + qd * 4;
#pragma unroll
    for (int c = 0; c < 8; ++c)
#pragma unroll
        for (int r = 0; r < 4; ++r) {
            int row = row0 + r;
            if (row < M) C[(size_t)row * 128 + c * 16 + m] = f2bf(acc[c][r]);
        }
}

// ---------------- GEMM (MFMA): C = bf16(A @ W), A bf16 ---------------------

template<int NOUT>
__global__ __launch_bounds__(256) void k_gemmB(
        const unsigned short* __restrict__ A,   // [M][128] bf16
        const unsigned short* __restrict__ Wt,  // [NOUT][128] bf16
        unsigned short* __restrict__ C,         // [M][NOUT] bf16
        int M) {
    constexpr int NT  = NOUT / 16;
    constexpr int STR = 136;
    __shared__ unsigned short sWt[NOUT * STR];

    const int tid = threadIdx.x;
#pragma unroll
    for (int i = 0; i < NOUT * 16 / 256; ++i) {
        int c = i * 256 + tid;
        int row = c >> 4, col = (c & 15) * 8;
        *(uint4*)&sWt[row * STR + col] = *(const uint4*)&Wt[row * 128 + col];
    }

    const int wv = tid >> 6;
    const int ln = tid & 63;
    const int m  = ln & 15;
    const int qd = ln >> 4;

    int gr  = blockIdx.x * 64 + wv * 16 + m;
    int grc = (gr < M) ? gr : (M - 1);
    bf16x8 af[4];
#pragma unroll
    for (int s = 0; s < 4; ++s)
        af[s] = *(const bf16x8*)&A[(size_t)grc * 128 + s * 32 + qd * 8];

    __syncthreads();

    floatx4 acc[NT];
#pragma unroll
    for (int c = 0; c < NT; ++c) {
        acc[c] = (floatx4){0.f, 0.f, 0.f, 0.f};
#pragma unroll
        for (int s = 0; s < 4; ++s) {
            bf16x8 bf = *(const bf16x8*)&sWt[(c * 16 + m) * STR + s * 32 + qd * 8];
            acc[c] = __builtin_amdgcn_mfma_f32_16x16x32_bf16(af[s], bf, acc[c], 0, 0, 0);
        }
    }

    int row0 = blockIdx.x * 64 + wv * 16 + qd * 4;
#pragma unroll
    for (int c = 0; c < NT; ++c)
#pragma unroll
        for (int r = 0; r < 4; ++r) {
            int row = row0 + r;
            if (row < M) C[(size_t)row * NOUT + c * 16 + m] = f2bf(acc[c][r]);
        }
}

// ---------------- Column-partitioned aggregation ---------------------------
// grp = blockIdx & 3 -> 32-col slice (3.2MB, fits one XCD L2; blocks
// round-robin XCDs by blockIdx%8 so XCD k serves slice k%4). 128 thr =
// 2 waves, 8 nodes/wave. 4 edge-groups x 16 lanes; lane carries 2 cols
// (4B); per 16-edge batch: 1 broadcast uint4 meta + 4 single-line (64B)
// gathers; zero branches (sentinel padding). h' slice -> bf16 out.

__global__ __launch_bounds__(128, 8) void k_aggc(
        const unsigned short* __restrict__ sup,  // [NN][128] bf16
        const int2* __restrict__ begend, const unsigned* __restrict__ es,
        const float* __restrict__ bias,
        unsigned short* __restrict__ out,        // [NN][128] bf16
        int M) {
    const int grp  = blockIdx.x & 3;
    const int tile = blockIdx.x >> 2;
    const int col0 = grp * 32;

    const int tid = threadIdx.x;
    const int wv  = tid >> 6;        // 0..1
    const int ln  = tid & 63;
    const int g   = ln >> 4;         // edge group 0..3
    const int l   = ln & 15;         // 2-col slot

    const int n0 = tile * 16;
    int2 be = begend[n0 + wv * 8];

    for (int nn = 0; nn < 8; ++nn) {
        int n = n0 + wv * 8 + nn;
        int beg = be.x, endp = be.y;
        if (nn < 7) be = begend[n + 1];
        float a0 = 0.f, a1 = 0.f;
        if (endp > beg) {
            int e = beg;
            uint4 mv = *(const uint4*)&es[e + 4 * g];
            for (;;) {
                unsigned r0 = *(const unsigned*)&sup[(size_t)(mv.x & 0xffffu) * 128 + col0 + l * 2];
                unsigned r1 = *(const unsigned*)&sup[(size_t)(mv.y & 0xffffu) * 128 + col0 + l * 2];
                unsigned r2 = *(const unsigned*)&sup[(size_t)(mv.z & 0xffffu) * 128 + col0 + l * 2];
                unsigned r3 = *(const unsigned*)&sup[(size_t)(mv.w & 0xffffu) * 128 + col0 + l * 2];
                float w0 = bfhi(mv.x), w1 = bfhi(mv.y);
                float w2 = bfhi(mv.z), w3 = bfhi(mv.w);
                e += 16;
                bool more = e < endp;
                uint4 mn = *(const uint4*)&es[e + 4 * g];  // sentinel-safe
                a0 = fmaf(w0, bflo(r0), a0); a1 = fmaf(w0, bfhi(r0), a1);
                a0 = fmaf(w1, bflo(r1), a0); a1 = fmaf(w1, bfhi(r1), a1);
                a0 = fmaf(w2, bflo(r2), a0); a1 = fmaf(w2, bfhi(r2), a1);
                a0 = fmaf(w3, bflo(r3), a0); a1 = fmaf(w3, bfhi(r3), a1);
                mv = mn;
                if (!more) break;
            }
            a0 += __shfl_xor(a0, 16, 64); a1 += __shfl_xor(a1, 16, 64);
            a0 += __shfl_xor(a0, 32, 64); a1 += __shfl_xor(a1, 32, 64);
        }
        if (g == 0 && n < M) {
            a0 = fmaxf(a0 + bias[col0 + l * 2],     0.f);
            a1 = fmaxf(a1 + bias[col0 + l * 2 + 1], 0.f);
            unsigned pk = (unsigned)f2bf(a0) | ((unsigned)f2bf(a1) << 16);
            *(unsigned*)&out[(size_t)n * 128 + col0 + l * 2] = pk;
        }
    }
}

// Final layer (64 cols, fp32 out, no relu): 2 column groups of 32.
__global__ __launch_bounds__(128, 8) void k_agg64c(
        const unsigned short* __restrict__ sup,  // [NN][64] bf16
        const int2* __restrict__ begend, const unsigned* __restrict__ es,
        const float* __restrict__ bias, float* __restrict__ out) {
    const int grp  = blockIdx.x & 1;
    const int tile = blockIdx.x >> 1;
    const int col0 = grp * 32;

    const int tid = threadIdx.x;
    const int wv  = tid >> 6;
    const int ln  = tid & 63;
    const int g   = ln >> 4;
    const int l   = ln & 15;

    const int n0 = tile * 16;
    int2 be = begend[n0 + wv * 8];

    for (int nn = 0; nn < 8; ++nn) {
        int n = n0 + wv * 8 + nn;
        int beg = be.x, endp = be.y;
        if (nn < 7) be = begend[n + 1];
        float a0 = 0.f, a1 = 0.f;
        if (endp > beg) {
            int e = beg;
            uint4 mv = *(const uint4*)&es[e + 4 * g];
            for (;;) {
                unsigned r0 = *(const unsigned*)&sup[(size_t)(mv.x & 0xffffu) * 64 + col0 + l * 2];
                unsigned r1 = *(const unsigned*)&sup[(size_t)(mv.y & 0xffffu) * 64 + col0 + l * 2];
                unsigned r2 = *(const unsigned*)&sup[(size_t)(mv.z & 0xffffu) * 64 + col0 + l * 2];
                unsigned r3 = *(const unsigned*)&sup[(size_t)(mv.w & 0xffffu) * 64 + col0 + l * 2];
                float w0 = bfhi(mv.x), w1 = bfhi(mv.y);
                float w2 = bfhi(mv.z), w3 = bfhi(mv.w);
                e += 16;
                bool more = e < endp;
                uint4 mn = *(const uint4*)&es[e + 4 * g];  // sentinel-safe
                a0 = fmaf(w0, bflo(r0), a0); a1 = fmaf(w0, bfhi(r0), a1);
                a0 = fmaf(w1, bflo(r1), a0); a1 = fmaf(w1, bfhi(r1), a1);
                a0 = fmaf(w2, bflo(r2), a0); a1 = fmaf(w2, bfhi(r2), a1);
                a0 = fmaf(w3, bflo(r3), a0); a1 = fmaf(w3, bfhi(r3), a1);
                mv = mn;
                if (!more) break;
            }
            a0 += __shfl_xor(a0, 16, 64); a1 += __shfl_xor(a1, 16, 64);
            a0 += __shfl_xor(a0, 32, 64); a1 += __shfl_xor(a1, 32, 64);
        }
        if (g == 0 && n < NN) {
            float2 o = make_float2(a0 + bias[col0 + l * 2],
                                   a1 + bias[col0 + l * 2 + 1]);
            *(float2*)&out[(size_t)n * 64 + col0 + l * 2] = o;
        }
    }
}

// ---------------- launch ----------------

extern "C" void kernel_launch(void* const* d_in, const int* in_sizes, int n_in,
                              void* d_out, int out_size, void* d_ws, size_t ws_size,
                              hipStream_t stream) {
    (void)in_sizes; (void)n_in; (void)out_size; (void)ws_size;

    const float* x    = (const float*)d_in[0];
    const int*   esrc = (const int*)d_in[1];
    const int*   edst = (const int*)d_in[2];
    const float* ew   = (const float*)d_in[3];
    const float* W0   = (const float*)d_in[4];
    const float* b0   = (const float*)d_in[5];
    const float* W1   = (const float*)d_in[6];
    const float* b1   = (const float*)d_in[7];
    const float* W2   = (const float*)d_in[8];
    const float* b2   = (const float*)d_in[9];
    const float* W3   = (const float*)d_in[10];
    const float* b3   = (const float*)d_in[11];

    char* p = (char*)d_ws;
    auto alloc = [&](size_t bytes) {
        char* r = p;
        p += (bytes + 511) & ~size_t(511);
        return r;
    };
    int*      bfill  = (int*)     alloc((size_t)NB * 4);
    int2*     begend = (int2*)    alloc((size_t)NN * 8);
    int2*     ep     = (int2*)    alloc((size_t)NB * CAP * 8);
    unsigned* es     = (unsigned*)alloc((size_t)NB * CAP * 4);
    unsigned short* sup = (unsigned short*)alloc((size_t)NN * 128 * 2);
    unsigned short* hb  = (unsigned short*)alloc((size_t)NN * 128 * 2);
    unsigned short* Wt0 = (unsigned short*)alloc((size_t)128 * 128 * 2);
    unsigned short* Wt1 = (unsigned short*)alloc((size_t)128 * 128 * 2);
    unsigned short* Wt2 = (unsigned short*)alloc((size_t)128 * 128 * 2);
    unsigned short* Wt3 = (unsigned short*)alloc((size_t)64 * 128 * 2);

    // --- weights + bfill zero, then binned edge sort + begend ---
    k_prep<<<449, 128, 0, stream>>>(W0, W1, W2, W3, Wt0, Wt1, Wt2, Wt3, bfill);
    k_part<<<PART_GRID, 256, 0, stream>>>(esrc, edst, ew, bfill, ep);
    k_sort<<<NB, 256, 0, stream>>>(ep, bfill, es, begend);

    const int gemm_grid = (NN + 63) / 64;        // 782
    const int aggc_grid = ((NN + 15) / 16) * 4;  // 12500
    const int a64_grid  = ((NN + 15) / 16) * 2;  // 6250

    // layer 0 GEMM: sup = bf16(x @ W0)
    k_gemm0<<<gemm_grid, 256, 0, stream>>>(x, Wt0, sup, NN);
    // layer 0 agg (+b0, relu) -> hb ; layer 1 GEMM -> sup
    k_aggc<<<aggc_grid, 128, 0, stream>>>(sup, begend, es, b0, hb, NN);
    k_gemmB<128><<<gemm_grid, 256, 0, stream>>>(hb, Wt1, sup, NN);
    // layer 1 agg -> hb ; layer 2 GEMM -> sup
    k_aggc<<<aggc_grid, 128, 0, stream>>>(sup, begend, es, b1, hb, NN);
    k_gemmB<128><<<gemm_grid, 256, 0, stream>>>(hb, Wt2, sup, NN);
    // layer 2 agg -> hb ; layer 3 GEMM (64 cols) -> sup
    k_aggc<<<aggc_grid, 128, 0, stream>>>(sup, begend, es, b2, hb, NN);
    k_gemmB<64><<<gemm_grid, 256, 0, stream>>>(hb, Wt3, sup, NN);
    // layer 3 agg + b3, no relu, fp32 out
    k_agg64c<<<a64_grid, 128, 0, stream>>>(sup, begend, es, b3, (float*)d_out);
}

// Round 14
// 241.887 us; speedup vs baseline: 1.5238x; 1.5238x over previous
//
#include <hip/hip_runtime.h>

// GCN: h' = relu(A @ (h @ W) + b) x3, last layer no relu.
// Round 14 = round 12 structure (best: 254.8us) + FP8 e4m3 sup for the three
// hidden layers. Rationale: agg is L2-fill-bytes bound (FETCH ~= 8 XCDs x
// footprint at ~1.9TB/s in every schedule variant; r13 proved L2 line=128B,
// so sub-row column slicing wastes fill). fp8 halves the footprint with rows
// still 128B = one line per 16-lane group. GEMM epilogues emit fp8 via HW
// cvt; agg unpacks via cvt_pk_f32_fp8. h' tile (MFMA A-operand) and final
// layer sup stay bf16. Edge lists sentinel-padded, 4B packed records.

constexpr int NN = 50000;          // nodes
constexpr int NE = 800000;         // edges
constexpr int NB = (NN + 127) >> 7;          // 391 buckets (dst >> 7)
constexpr int CAP = 4608;                    // padded bucket capacity
constexpr int PART_CHUNK = 4096;             // edges per partition block
constexpr int PART_GRID = (NE + PART_CHUNK - 1) / PART_CHUNK;  // 196

typedef __attribute__((ext_vector_type(8))) short bf16x8;
typedef __attribute__((ext_vector_type(4))) float floatx4;
typedef __attribute__((ext_vector_type(2))) float floatx2;

__device__ inline unsigned short f2bf(float f) {          // RNE fp32->bf16
    unsigned u = __float_as_uint(f);
    u += 0x7fffu + ((u >> 16) & 1u);
    return (unsigned short)(u >> 16);
}
__device__ inline float bflo(unsigned v) { return __uint_as_float(v << 16); }
__device__ inline float bfhi(unsigned v) { return __uint_as_float(v & 0xffff0000u); }
__device__ inline unsigned char f2fp8(float f) {          // fp32 -> e4m3 (HW)
    return (unsigned char)(__builtin_amdgcn_cvt_pk_fp8_f32(f, f, 0, false) & 0xff);
}

// ---------------- binned edge sort (padded buckets) ----------------

__global__ __launch_bounds__(256) void k_part(
        const int* __restrict__ src, const int* __restrict__ dst,
        const float* __restrict__ w, int* __restrict__ bfill,
        int2* __restrict__ ep) {
    __shared__ int hist[NB], base[NB], off[NB];
    int tid = threadIdx.x;
    for (int b = tid; b < NB; b += 256) { hist[b] = 0; off[b] = 0; }
    __syncthreads();

    int e0 = blockIdx.x * PART_CHUNK;
    int  sreg[16]; int wreg[16]; short breg[16];
#pragma unroll
    for (int i = 0; i < 16; ++i) {
        int e = e0 + i * 256 + tid;
        if (e < NE) {
            int d = dst[e];
            int b = d >> 7;
            sreg[i] = (src[e] & 0xffff) | ((d & 127) << 16);
            wreg[i] = __float_as_int(w[e]);
            breg[i] = (short)b;
            atomicAdd(&hist[b], 1);
        } else breg[i] = -1;
    }
    __syncthreads();
    for (int b = tid; b < NB; b += 256)
        base[b] = b * CAP + atomicAdd(&bfill[b], hist[b]);
    __syncthreads();
#pragma unroll
    for (int i = 0; i < 16; ++i) {
        if (breg[i] >= 0) {
            int b = breg[i];
            int p = atomicAdd(&off[b], 1);
            ep[base[b] + p] = make_int2(sreg[i], wreg[i]);
        }
    }
}

// Within-bucket dst sort with per-node padding to multiple of 16.
// Emits packed 4B records: src16 | bf16(w)<<16; pad slots are 0 (w=0).
__global__ __launch_bounds__(256) void k_sort(
        const int2* __restrict__ ep, const int* __restrict__ bfill,
        unsigned* __restrict__ es, int2* __restrict__ begend) {
    __shared__ int cnt[128], base[128], fl[128];
    __shared__ int s_total;
    int b  = blockIdx.x;
    int n0 = b << 7;
    int nn = min(128, NN - n0);
    int t  = threadIdx.x;
    if (t < 128) { cnt[t] = 0; fl[t] = 0; }
    __syncthreads();
    int bbase = b * CAP;
    int beg = bbase, end = bbase + bfill[b];
    for (int e = beg + t; e < end; e += 256)
        atomicAdd(&cnt[(ep[e].x >> 16) & 127], 1);
    __syncthreads();
    int cp = (t < 128) ? ((cnt[t] + 15) & ~15) : 0;
    if (t < 128) base[t] = cp;
    __syncthreads();
    for (int off = 1; off < 128; off <<= 1) {
        int add = (t >= off && t < 128) ? base[t - off] : 0;
        __syncthreads();
        if (t < 128) base[t] += add;     // inclusive scan of padded counts
        __syncthreads();
    }
    if (t == 127) s_total = base[127];
    __syncthreads();
    int total = s_total;
    for (int i = t; i < total + 16; i += 256) es[bbase + i] = 0u;
    if (t < nn) {
        int off = base[t] - cp;
        begend[n0 + t] = make_int2(bbase + off, bbase + off + cp);
    }
    __syncthreads();
    for (int e = beg + t; e < end; e += 256) {
        int2 v = ep[e];
        int d = (v.x >> 16) & 127;
        int off = base[d] - ((cnt[d] + 15) & ~15);
        int pos = bbase + off + atomicAdd(&fl[d], 1);
        es[pos] = (unsigned)(v.x & 0xffff) |
                  ((unsigned)f2bf(__int_as_float(v.y)) << 16);
    }
}

// ---------------- weight transpose+convert + bfill zero --------------------

__global__ void k_prep(
        const float* __restrict__ W0, const float* __restrict__ W1,
        const float* __restrict__ W2, const float* __restrict__ W3,
        unsigned short* __restrict__ T0, unsigned short* __restrict__ T1,
        unsigned short* __restrict__ T2, unsigned short* __restrict__ T3,
        int* __restrict__ bfill) {
    int b = blockIdx.x;              // 0..448
    if (b == 448) {
        for (int i = threadIdx.x; i < NB; i += 128) bfill[i] = 0;
        return;
    }
    const float* W; unsigned short* T; int N, n;
    if (b < 128)      { W = W0; T = T0; N = 128; n = b; }
    else if (b < 256) { W = W1; T = T1; N = 128; n = b - 128; }
    else if (b < 384) { W = W2; T = T2; N = 128; n = b - 256; }
    else              { W = W3; T = T3; N = 64;  n = b - 384; }
    int k = threadIdx.x;             // 0..127
    T[n * 128 + k] = f2bf(W[(size_t)k * N + n]);
}

// ---------------- GEMM 0 (MFMA): sup = fp8(x @ W0), x fp32 -----------------

__device__ inline bf16x8 ldA_f32(const float* A, size_t off) {
    float4 u = *(const float4*)&A[off];
    float4 v = *(const float4*)&A[off + 4];
    bf16x8 r;
    r[0] = (short)f2bf(u.x); r[1] = (short)f2bf(u.y);
    r[2] = (short)f2bf(u.z); r[3] = (short)f2bf(u.w);
    r[4] = (short)f2bf(v.x); r[5] = (short)f2bf(v.y);
    r[6] = (short)f2bf(v.z); r[7] = (short)f2bf(v.w);
    return r;
}

__global__ __launch_bounds__(256) void k_gemm0(
        const float* __restrict__ A,            // [M][128] fp32
        const unsigned short* __restrict__ Wt,  // [128][128] bf16
        unsigned char* __restrict__ C,          // [M][128] fp8
        int M) {
    constexpr int STR = 136;
    __shared__ unsigned short sWt[128 * STR];

    const int tid = threadIdx.x;
#pragma unroll
    for (int i = 0; i < 8; ++i) {
        int c = i * 256 + tid;
        int row = c >> 4, col = (c & 15) * 8;
        *(uint4*)&sWt[row * STR + col] = *(const uint4*)&Wt[row * 128 + col];
    }

    const int wv = tid >> 6;
    const int ln = tid & 63;
    const int m  = ln & 15;
    const int qd = ln >> 4;

    int gr  = blockIdx.x * 64 + wv * 16 + m;
    int grc = (gr < M) ? gr : (M - 1);
    bf16x8 af[4];
#pragma unroll
    for (int s = 0; s < 4; ++s)
        af[s] = ldA_f32(A, (size_t)grc * 128 + s * 32 + qd * 8);

    __syncthreads();

    floatx4 acc[8];
#pragma unroll
    for (int c = 0; c < 8; ++c) {
        acc[c] = (floatx4){0.f, 0.f, 0.f, 0.f};
#pragma unroll
        for (int s = 0; s < 4; ++s) {
            bf16x8 bf = *(const bf16x8*)&sWt[(c * 16 + m) * STR + s * 32 + qd * 8];
            acc[c] = __builtin_amdgcn_mfma_f32_16x16x32_bf16(af[s], bf, acc[c], 0, 0, 0);
        }
    }

    int row0 = blockIdx.x * 64 + wv * 16 + qd * 4;
#pragma unroll
    for (int c = 0; c < 8; ++c)
#pragma unroll
        for (int r = 0; r < 4; ++r) {
            int row = row0 + r;
            if (row < M) C[(size_t)row * 128 + c * 16 + m] = f2fp8(acc[c][r]);
        }
}

// ---------------- Fused agg(layer i) + GEMM(layer i+1) ---------------------
// 16-node tile, 128 threads = 2 waves, 8 nodes per wave. Agg: 4 groups of
// 16 lanes; group g owns edges e+4g..e+4g+3 of each 16-edge batch; per batch
// ONE broadcast uint4 meta load + 4 row-gathers (fp8 rows: 8B/lane, 128B =
// one L2 line per group); zero branches (sentinel padding). shfl_xor(16,32)
// combines; relu+bias -> bf16 tile in LDS. GEMM: wave = N-half; B-fragments
// straight from L2-hot Wt. CT: fp8 (hidden layers) or bf16 (layer 3).

#define FMAP8(W, R)                                                             \
    { floatx2 p0 = __builtin_amdgcn_cvt_pk_f32_fp8((int)(R).x, false);          \
      floatx2 p1 = __builtin_amdgcn_cvt_pk_f32_fp8((int)(R).x, true);           \
      floatx2 p2 = __builtin_amdgcn_cvt_pk_f32_fp8((int)(R).y, false);          \
      floatx2 p3 = __builtin_amdgcn_cvt_pk_f32_fp8((int)(R).y, true);           \
      acc[0] = fmaf(W, p0.x, acc[0]); acc[1] = fmaf(W, p0.y, acc[1]);           \
      acc[2] = fmaf(W, p1.x, acc[2]); acc[3] = fmaf(W, p1.y, acc[3]);           \
      acc[4] = fmaf(W, p2.x, acc[4]); acc[5] = fmaf(W, p2.y, acc[5]);           \
      acc[6] = fmaf(W, p3.x, acc[6]); acc[7] = fmaf(W, p3.y, acc[7]); }

template<int NOUT, typename CT>
__global__ __launch_bounds__(128, 4) void k_fused(
        const unsigned char* __restrict__ sup,   // [NN][128] fp8
        const int2* __restrict__ begend, const unsigned* __restrict__ es,
        const float* __restrict__ bias,          // layer-i bias (relu applied)
        const unsigned short* __restrict__ Wt,   // [NOUT][128] bf16
        CT* __restrict__ C,                      // [M][NOUT] fp8 or bf16
        int M) {
    constexpr int NT  = NOUT / 16;
    constexpr int STR = 136;
    __shared__ unsigned short hT[16 * STR];

    const int tid = threadIdx.x;
    const int wv  = tid >> 6;        // 0..1
    const int ln  = tid & 63;
    const int g   = ln >> 4;         // edge group 0..3
    const int l   = ln & 15;         // 8-col slot

    const int n0 = blockIdx.x * 16;
    int2 be = begend[n0 + wv * 8];

    for (int nn = 0; nn < 8; ++nn) {
        int n = n0 + wv * 8 + nn;
        int beg = be.x, endp = be.y;
        if (nn < 7) be = begend[n + 1];          // prefetch next node's range
        float acc[8] = {0.f, 0.f, 0.f, 0.f, 0.f, 0.f, 0.f, 0.f};
        if (endp > beg) {
            int e = beg;
            uint4 mv = *(const uint4*)&es[e + 4 * g];
            for (;;) {
                uint2 r0 = *(const uint2*)&sup[(size_t)(mv.x & 0xffffu) * 128 + l * 8];
                uint2 r1 = *(const uint2*)&sup[(size_t)(mv.y & 0xffffu) * 128 + l * 8];
                uint2 r2 = *(const uint2*)&sup[(size_t)(mv.z & 0xffffu) * 128 + l * 8];
                uint2 r3 = *(const uint2*)&sup[(size_t)(mv.w & 0xffffu) * 128 + l * 8];
                float w0 = bfhi(mv.x), w1 = bfhi(mv.y);
                float w2 = bfhi(mv.z), w3 = bfhi(mv.w);
                e += 16;
                bool more = e < endp;
                uint4 mn = *(const uint4*)&es[e + 4 * g];  // sentinel-safe
                FMAP8(w0, r0); FMAP8(w1, r1); FMAP8(w2, r2); FMAP8(w3, r3);
                mv = mn;
                if (!more) break;
            }
#pragma unroll
            for (int f = 0; f < 8; ++f) {
                acc[f] += __shfl_xor(acc[f], 16, 64);
                acc[f] += __shfl_xor(acc[f], 32, 64);
            }
        }
        if (g == 0) {
            unsigned pk[4];
#pragma unroll
            for (int q = 0; q < 4; ++q) {
                float a0 = fmaxf(acc[2 * q]     + bias[l * 8 + 2 * q],     0.f);
                float a1 = fmaxf(acc[2 * q + 1] + bias[l * 8 + 2 * q + 1], 0.f);
                pk[q] = (unsigned)f2bf(a0) | ((unsigned)f2bf(a1) << 16);
            }
            *(uint4*)&hT[(wv * 8 + nn) * STR + l * 8] = *(uint4*)pk;
        }
    }
    __syncthreads();

    // GEMM phase: wave = N-half. 16 rows x 64 cols per wave.
    const int m_ = ln & 15, qd = ln >> 4;
    const int c0 = wv * (NT / 2);
    bf16x8 af[4];
#pragma unroll
    for (int s = 0; s < 4; ++s)
        af[s] = *(const bf16x8*)&hT[m_ * STR + s * 32 + qd * 8];

    floatx4 acc2[NT / 2];
#pragma unroll
    for (int c = 0; c < NT / 2; ++c) {
        acc2[c] = (floatx4){0.f, 0.f, 0.f, 0.f};
#pragma unroll
        for (int s = 0; s < 4; ++s) {
            bf16x8 bf = *(const bf16x8*)&Wt[(size_t)((c0 + c) * 16 + m_) * 128 + s * 32 + qd * 8];
            acc2[c] = __builtin_amdgcn_mfma_f32_16x16x32_bf16(af[s], bf, acc2[c], 0, 0, 0);
        }
    }
    int row0 = n0 + qd * 4;
#pragma unroll
    for (int c = 0; c < NT / 2; ++c)
#pragma unroll
        for (int r = 0; r < 4; ++r) {
            int row = row0 + r;
            if (row < M) {
                if constexpr (sizeof(CT) == 1)
                    C[(size_t)row * NOUT + (c0 + c) * 16 + m_] = (CT)f2fp8(acc2[c][r]);
                else
                    C[(size_t)row * NOUT + (c0 + c) * 16 + m_] = (CT)f2bf(acc2[c][r]);
            }
        }
}

// ---------------- Final aggregate (layer 3): out fp32, no relu -------------
// sup64 is bf16 (precision: last stage feeds output directly). 8 groups of
// 8 lanes; one broadcast uint2 meta + 2 row-gathers per 16-edge batch.

#define FMA8(W, R)                                                              \
    acc[0] = fmaf(W, bflo((R).x), acc[0]); acc[1] = fmaf(W, bfhi((R).x), acc[1]); \
    acc[2] = fmaf(W, bflo((R).y), acc[2]); acc[3] = fmaf(W, bfhi((R).y), acc[3]); \
    acc[4] = fmaf(W, bflo((R).z), acc[4]); acc[5] = fmaf(W, bfhi((R).z), acc[5]); \
    acc[6] = fmaf(W, bflo((R).w), acc[6]); acc[7] = fmaf(W, bfhi((R).w), acc[7]);

__global__ __launch_bounds__(256, 4) void k_agg64(
        const unsigned short* __restrict__ sup,  // [NN][64] bf16
        const int2* __restrict__ begend, const unsigned* __restrict__ es,
        const float* __restrict__ bias, float* __restrict__ out) {
    int n  = blockIdx.x * 4 + (threadIdx.x >> 6);
    int ln = threadIdx.x & 63;
    int g  = ln >> 3, l = ln & 7;
    int2 be = begend[n];
    int beg = be.x, endp = be.y;
    float acc[8] = {0.f, 0.f, 0.f, 0.f, 0.f, 0.f, 0.f, 0.f};
    if (endp > beg) {
        int e = beg;
        uint2 mv = *(const uint2*)&es[e + 2 * g];
        for (;;) {
            uint4 r0 = *(const uint4*)&sup[(size_t)(mv.x & 0xffffu) * 64 + l * 8];
            uint4 r1 = *(const uint4*)&sup[(size_t)(mv.y & 0xffffu) * 64 + l * 8];
            float w0 = bfhi(mv.x), w1 = bfhi(mv.y);
            e += 16;
            bool more = e < endp;
            uint2 mn = *(const uint2*)&es[e + 2 * g];  // sentinel-safe
            FMA8(w0, r0); FMA8(w1, r1);
            mv = mn;
            if (!more) break;
        }
    }
#pragma unroll
    for (int f = 0; f < 8; ++f) {
        acc[f] += __shfl_xor(acc[f], 8, 64);
        acc[f] += __shfl_xor(acc[f], 16, 64);
        acc[f] += __shfl_xor(acc[f], 32, 64);
    }
    if (g == 0) {
        float4 o0 = make_float4(acc[0] + bias[l * 8],     acc[1] + bias[l * 8 + 1],
                                acc[2] + bias[l * 8 + 2], acc[3] + bias[l * 8 + 3]);
        float4 o1 = make_float4(acc[4] + bias[l * 8 + 4], acc[5] + bias[l * 8 + 5],
                                acc[6] + bias[l * 8 + 6], acc[7] + bias[l * 8 + 7]);
        *(float4*)&out[(size_t)n * 64 + l * 8]     = o0;
        *(float4*)&out[(size_t)n * 64 + l * 8 + 4] = o1;
    }
}

// ---------------- launch ----------------

extern "C" void kernel_launch(void* const* d_in, const int* in_sizes, int n_in,
                              void* d_out, int out_size, void* d_ws, size_t ws_size,
                              hipStream_t stream) {
    (void)in_sizes; (void)n_in; (void)out_size; (void)ws_size;

    const float* x    = (const float*)d_in[0];
    const int*   esrc = (const int*)d_in[1];
    const int*   edst = (const int*)d_in[2];
    const float* ew   = (const float*)d_in[3];
    const float* W0   = (const float*)d_in[4];
    const float* b0   = (const float*)d_in[5];
    const float* W1   = (const float*)d_in[6];
    const float* b1   = (const float*)d_in[7];
    const float* W2   = (const float*)d_in[8];
    const float* b2   = (const float*)d_in[9];
    const float* W3   = (const float*)d_in[10];
    const float* b3   = (const float*)d_in[11];

    char* p = (char*)d_ws;
    auto alloc = [&](size_t bytes) {
        char* r = p;
        p += (bytes + 511) & ~size_t(511);
        return r;
    };
    int*      bfill  = (int*)     alloc((size_t)NB * 4);
    int2*     begend = (int2*)    alloc((size_t)NN * 8);
    int2*     ep     = (int2*)    alloc((size_t)NB * CAP * 8);
    unsigned* es     = (unsigned*)alloc((size_t)NB * CAP * 4);
    unsigned char*  s8a = (unsigned char*) alloc((size_t)NN * 128);
    unsigned char*  s8b = (unsigned char*) alloc((size_t)NN * 128);
    unsigned short* s16 = (unsigned short*)alloc((size_t)NN * 64 * 2);
    unsigned short* Wt0 = (unsigned short*)alloc((size_t)128 * 128 * 2);
    unsigned short* Wt1 = (unsigned short*)alloc((size_t)128 * 128 * 2);
    unsigned short* Wt2 = (unsigned short*)alloc((size_t)128 * 128 * 2);
    unsigned short* Wt3 = (unsigned short*)alloc((size_t)64 * 128 * 2);

    // --- weights + bfill zero, then binned edge sort + begend ---
    k_prep<<<449, 128, 0, stream>>>(W0, W1, W2, W3, Wt0, Wt1, Wt2, Wt3, bfill);
    k_part<<<PART_GRID, 256, 0, stream>>>(esrc, edst, ew, bfill, ep);
    k_sort<<<NB, 256, 0, stream>>>(ep, bfill, es, begend);

    const int g0_grid = (NN + 63) / 64;     // 782
    const int f_grid  = (NN + 15) / 16;     // 3125
    const int a_grid  = (NN + 3) / 4;       // 12500

    // layer 0 GEMM: s8a = fp8(x @ W0)
    k_gemm0<<<g0_grid, 256, 0, stream>>>(x, Wt0, s8a, NN);
    // fused: agg0(+b0,relu) -> gemm1 -> s8b (fp8)
    k_fused<128, unsigned char><<<f_grid, 128, 0, stream>>>(s8a, begend, es, b0, Wt1, s8b, NN);
    // fused: agg1(+b1,relu) -> gemm2 -> s8a (fp8)
    k_fused<128, unsigned char><<<f_grid, 128, 0, stream>>>(s8b, begend, es, b1, Wt2, s8a, NN);
    // fused: agg2(+b2,relu) -> gemm3 (64 cols) -> s16 (bf16)
    k_fused<64, unsigned short><<<f_grid, 128, 0, stream>>>(s8a, begend, es, b2, Wt3, s16, NN);
    // final: agg3 + b3, no relu, fp32 out
    k_agg64<<<a_grid, 256, 0, stream>>>(s16, begend, es, b3, (float*)d_out);
}